// Round 7
// baseline (476.978 us; speedup 1.0000x reference)
//
#include <hip/hip_runtime.h>
#include <hip/hip_bf16.h>
#include <stdint.h>
#include <stddef.h>

// ---------- types ----------
typedef __attribute__((ext_vector_type(8)))  __bf16 bf16x8;   // MFMA A/B frag (4 VGPRs)
typedef __attribute__((ext_vector_type(4)))  float  f32x4;    // 16x16 MFMA C/D frag
typedef __attribute__((ext_vector_type(8)))  unsigned short ushort8;

typedef const void __attribute__((address_space(1)))* as1_cvp;
typedef void       __attribute__((address_space(3)))* as3_vp;

__device__ __forceinline__ void gload_lds16(const void* g, void* l) {
    // width=16 -> global_load_lds_dwordx4. LDS dest = wave-uniform base + lane*16.
    __builtin_amdgcn_global_load_lds((as1_cvp)g, (as3_vp)l, 16, 0, 0);
}

__device__ __forceinline__ unsigned short f2bf(float f) {
    union { float f; unsigned u; } v; v.f = f;
    unsigned r = v.u + 0x7fffu + ((v.u >> 16) & 1u);   // RNE
    return (unsigned short)(r >> 16);
}

// ---------- kernel 1 (fused prep): blocks [0,nW) -> Wb row; blocks [nW,..) -> x cast ----------
// UNCHANGED (isolating the GEMM change).
__global__ __launch_bounds__(256) void prep_kernel(
    const float* __restrict__ x,
    const float* __restrict__ W,
    const float* __restrict__ A1, const float* __restrict__ B1,
    const float* __restrict__ A2, const float* __restrict__ B2,
    unsigned short* __restrict__ Xb, unsigned short* __restrict__ Wb,
    int d, int nW, int n8)
{
    int blk = blockIdx.x;
    if (blk < nW) {
        int o  = blk;
        int k0 = threadIdx.x * 8;
        const float4* wrow = (const float4*)(W + (size_t)o * d + k0);
        float4 w0 = wrow[0], w1 = wrow[1];
        float acc[8] = {w0.x, w0.y, w0.z, w0.w, w1.x, w1.y, w1.z, w1.w};
        if (o >= d) {                               // block-uniform branch
            const float* A  = (o < 2 * d) ? A1 : A2;    // [8, d]
            const float* Bm = (o < 2 * d) ? B1 : B2;    // [d, 8]
            int r0 = o - ((o < 2 * d) ? d : 2 * d);
#pragma unroll
            for (int r = 0; r < 8; ++r) {
                float bb = Bm[(size_t)r0 * 8 + r];
                const float4* arow = (const float4*)(A + (size_t)r * d + k0);
                float4 a0 = arow[0], a1 = arow[1];
                acc[0] += bb * a0.x; acc[1] += bb * a0.y;
                acc[2] += bb * a0.z; acc[3] += bb * a0.w;
                acc[4] += bb * a1.x; acc[5] += bb * a1.y;
                acc[6] += bb * a1.z; acc[7] += bb * a1.w;
            }
        }
        ushort8 ov;
#pragma unroll
        for (int c = 0; c < 8; ++c) ov[c] = f2bf(acc[c]);
        ((ushort8*)(Wb + (size_t)o * d))[threadIdx.x] = ov;
    } else {
        int i = (blk - nW) * 256 + threadIdx.x;
        if (i >= n8) return;
        const float4* s = (const float4*)x + (size_t)i * 2;
        float4 a = s[0], c = s[1];
        ushort8 o;
        o[0] = f2bf(a.x); o[1] = f2bf(a.y); o[2] = f2bf(a.z); o[3] = f2bf(a.w);
        o[4] = f2bf(c.x); o[5] = f2bf(c.y); o[6] = f2bf(c.z); o[7] = f2bf(c.w);
        ((ushort8*)Xb)[i] = o;
    }
}

// ---------- kernel 2: 256x256, BK=64, quadrant schedule, 16x16x32 MFMA, DEEP staging ----------
// 512 thr = 8 waves (2M x 4N); wave tile 128x64 = acc[8][4] of f32x4.
// R5 measured: conflicts=0, MfmaUtil 42%, stall dominated by the ph4 vmcnt wait whose
// youngest retired load was only 2 phases old. CHANGE: deepen staging (register-free):
//  v.ph1: stage A(v+1) j2,j3 -> buf^1   [j0,j1 staged at (v-1).ph4]
//  v.ph2: (no stages)
//  v.ph3: stage B(v+2) j0,j1 -> buf
//  v.ph4: stage B(v+2) j2,j3 + A(v+2) j0,j1 -> buf; vmcnt(6); BAR; MFMA
// Youngest load at retire = A(v+1)j2,j3 issued v.ph1 = 3 phases old; up to 14 in flight.
// WAR audit (reads lgkm'd before the MFMA that precedes each stage's barrier):
//  A(v+2)j0,j1 @v.ph4 over A(v)j0 (dead v.ph1) / j1 (dead v.ph3, 1 bar + lgkm) OK
//  A(v+1)j2,j3 @v.ph1 over A(v-1)j2 (dead (v-1).ph1) / j3 (dead (v-1).ph3) OK
//  B(v+2)j0,j1 @v.ph3 over B(v)* (all dead after v.ph2: ch0 read ph1, ch1 read ph2) OK
//  B(v+2)j2,j3 @v.ph4: same. OK
// RAW: vmcnt(6) at v.ph4 retires A(v+1) fully (j0,j1 from (v-1).ph4 and j2,j3 from v.ph1)
//  and B(v+1) (from (v-1).ph3/ph4); leaves {B(v+2)x4, A(v+2)j0,j1} = 6. Steady invariant OK.
constexpr int BM = 256, BN = 256, BK = 64;
constexpr int KK = 2048, NN = 6144;       // fixed by problem shape
constexpr int TT = KK / BK;               // 32 K-tiles

__global__ __launch_bounds__(512, 2) void gemm256_kernel(
    const unsigned short* __restrict__ Xb,
    const unsigned short* __restrict__ Wb,
    const float* __restrict__ bias,
    float* __restrict__ out,
    int M)
{
    __shared__ __align__(16) unsigned short As[2][BM * BK];   // 2 x 32 KiB
    __shared__ __align__(16) unsigned short Bs[2][BN * BK];   // 2 x 32 KiB

    const int tid  = threadIdx.x;
    const int wave = tid >> 6;
    const int lane = tid & 63;
    const int l15  = lane & 15;
    const int l4   = lane >> 4;       // 0..3 -> k-group
    const int wrow = wave >> 2;       // 0..1  -> row offset *128
    const int wcol = wave & 3;        // 0..3  -> col offset *64

    // ---- XCD-aware block swizzle (bijective: 768 % 8 == 0) ----
    int nwg = (int)gridDim.x;
    int bid = (int)blockIdx.x;
    int swz = bid;
    if ((nwg & 7) == 0) swz = (bid & 7) * (nwg >> 3) + (bid >> 3);
    const int ntn = NN / BN;          // 24
    const int bm = (swz / ntn) * BM;
    const int bn = (swz % ntn) * BN;

    // ---- staging per-thread constants: call = 64 rows x 8 chunks = 512 lanes ----
    // LDS slot p of row r holds global k-chunk p^(r&7); lane-linear dest (rule #21).
    const int rtid = tid >> 3;                     // row-in-call 0..63
    const int ctid = (tid & 7) ^ (rtid & 7);       // swizzled global chunk
    const size_t gA0 = (size_t)(bm + rtid) * KK + ctid * 8;
    const size_t gB0 = (size_t)(bn + rtid) * KK + ctid * 8;
    const int ldsW = wave * 512;                   // shorts: wave covers 8 rows/call

#define STAGE_A(t, j, buf) gload_lds16(Xb + gA0 + (size_t)(j) * 64 * KK + (size_t)(t) * BK, \
                                       &As[(buf)][(j) * 4096 + ldsW])
#define STAGE_B(t, j, buf) gload_lds16(Wb + gB0 + (size_t)(j) * 64 * KK + (size_t)(t) * BK, \
                                       &Bs[(buf)][(j) * 4096 + ldsW])

    // ---- fragment read offsets (shorts) ----
    // frag(row-tile rt, kstep ks): lane: row = base + rt*16 + l15, chunk c = ks*4 + l4,
    // slot = c ^ (row&7) = c ^ (lane&7). Measured: 0 bank conflicts.
    int slotk[2];
#pragma unroll
    for (int ks = 0; ks < 2; ++ks) slotk[ks] = ((ks * 4 + l4) ^ (lane & 7)) * 8;
    const int rowAb = (wrow * 128 + l15) * 64;
    const int rowBb = (wcol * 64 + l15) * 64;

    f32x4 acc[8][4];
#pragma unroll
    for (int i = 0; i < 8; ++i)
#pragma unroll
        for (int j = 0; j < 4; ++j)
#pragma unroll
            for (int r = 0; r < 4; ++r) acc[i][j][r] = 0.f;

    bf16x8 a[4][2], b0[2][2], b1[2][2];

#define LOAD_A4(SRC, rh) do { _Pragma("unroll") for (int rt = 0; rt < 4; ++rt)      \
        { _Pragma("unroll") for (int ks = 0; ks < 2; ++ks)                          \
            a[rt][ks] = *(const bf16x8*)&(SRC)[rowAb + ((rh) * 4 + rt) * 1024 + slotk[ks]]; } } while (0)
#define LOAD_B2(SRC, ch, DST) do { _Pragma("unroll") for (int c2 = 0; c2 < 2; ++c2) \
        { _Pragma("unroll") for (int ks = 0; ks < 2; ++ks)                          \
            DST[c2][ks] = *(const bf16x8*)&(SRC)[rowBb + ((ch) * 2 + c2) * 1024 + slotk[ks]]; } } while (0)
// 16 MFMA = quadrant (rh, ch): 8 independent acc, dependent pairs ks0->ks1.
#define MFMA_PH(rh, ch, BB) do {                                                    \
        __builtin_amdgcn_s_setprio(1);                                             \
        _Pragma("unroll") for (int ks = 0; ks < 2; ++ks)                           \
        _Pragma("unroll") for (int c2 = 0; c2 < 2; ++c2)                           \
        _Pragma("unroll") for (int rt = 0; rt < 4; ++rt)                           \
            acc[(rh) * 4 + rt][(ch) * 2 + c2] = __builtin_amdgcn_mfma_f32_16x16x32_bf16( \
                a[rt][ks], BB[c2][ks], acc[(rh) * 4 + rt][(ch) * 2 + c2], 0, 0, 0);     \
        __builtin_amdgcn_s_setprio(0); } while (0)
#define BAR() asm volatile("s_barrier" ::: "memory")

// S1 gates A(v+1)j2,j3 (valid v <= TT-2); S2 gates B(v+2)/A(v+2) (valid v <= TT-3).
#define GROUP16(v, QQ, S1, S2, VMW) do {                                           \
        const unsigned short* Aq = &As[(QQ)][0];                                   \
        const unsigned short* Bq = &Bs[(QQ)][0];                                   \
        /* ph1 */                                                                  \
        LOAD_A4(Aq, 0); LOAD_B2(Bq, 0, b0);                                        \
        if (S1) { STAGE_A((v) + 1, 2, (QQ) ^ 1); STAGE_A((v) + 1, 3, (QQ) ^ 1); }  \
        BAR();                                                                     \
        MFMA_PH(0, 0, b0);                                                         \
        BAR();                                                                     \
        /* ph2 */                                                                  \
        LOAD_B2(Bq, 1, b1);                                                        \
        BAR();                                                                     \
        MFMA_PH(0, 1, b1);                                                         \
        BAR();                                                                     \
        /* ph3 */                                                                  \
        LOAD_A4(Aq, 1);                                                            \
        if (S2) { STAGE_B((v) + 2, 0, (QQ)); STAGE_B((v) + 2, 1, (QQ)); }          \
        BAR();                                                                     \
        MFMA_PH(1, 1, b1);                                                         \
        BAR();                                                                     \
        /* ph4: deep stage burst, counted retire, then MFMA */                     \
        if (S2) { STAGE_B((v) + 2, 2, (QQ)); STAGE_B((v) + 2, 3, (QQ));            \
                  STAGE_A((v) + 2, 0, (QQ)); STAGE_A((v) + 2, 1, (QQ)); }          \
        if ((VMW) == 6)      asm volatile("s_waitcnt vmcnt(6)" ::: "memory");      \
        else if ((VMW) == 0) asm volatile("s_waitcnt vmcnt(0)" ::: "memory");      \
        BAR();                                                                     \
        MFMA_PH(1, 0, b0);                                                         \
        BAR();                                                                     \
    } while (0)

    // ---- prologue: A(0)x4, B(0)x4, B(1)x4, A(1)j0,j1 -> vmcnt(6) retires tile 0 ----
#pragma unroll
    for (int j = 0; j < 4; ++j) STAGE_A(0, j, 0);
#pragma unroll
    for (int j = 0; j < 4; ++j) STAGE_B(0, j, 0);
#pragma unroll
    for (int j = 0; j < 4; ++j) STAGE_B(1, j, 1);
    STAGE_A(1, 0, 1); STAGE_A(1, 1, 1);
    asm volatile("s_waitcnt vmcnt(6)" ::: "memory");
    BAR();

    // ---- main loop: steady pairs (compile-time buffer parity), then 2 tail tiles ----
    for (int vv = 0; vv < TT - 2; vv += 2) {       // TT-2 = 30, even
        GROUP16(vv,     0, 1, 1, 6);
        GROUP16(vv + 1, 1, 1, 1, 6);
    }
    GROUP16(TT - 2, 0, 1, 0, 0);                   // stages A(TT-1)j2,j3; drains all
    GROUP16(TT - 1, 1, 0, 0, -1);                  // last tile, no stages, no wait

#undef GROUP16
#undef BAR
#undef MFMA_PH
#undef LOAD_B2
#undef LOAD_A4
#undef STAGE_B
#undef STAGE_A

    // ---- epilogue: 16x16 C/D layout col=lane&15, row=(lane>>4)*4+reg (m89/m91) ----
#pragma unroll
    for (int ct = 0; ct < 4; ++ct) {
        int col = bn + wcol * 64 + ct * 16 + l15;
        float bv = bias[col];
#pragma unroll
        for (int rt = 0; rt < 8; ++rt) {
            int rbase = bm + wrow * 128 + rt * 16 + l4 * 4;
#pragma unroll
            for (int reg = 0; reg < 4; ++reg) {
                out[(size_t)(rbase + reg) * NN + col] = acc[rt][ct][reg] + bv;
            }
        }
    }
}

// ---------- launcher ----------
extern "C" void kernel_launch(void* const* d_in, const int* in_sizes, int n_in,
                              void* d_out, int out_size, void* d_ws, size_t ws_size,
                              hipStream_t stream) {
    const float* x  = (const float*)d_in[0];   // [4,2048,2048]
    const float* W  = (const float*)d_in[1];   // [6144,2048]
    const float* b  = (const float*)d_in[2];   // [6144]
    const float* A1 = (const float*)d_in[3];   // [8,2048]
    const float* B1 = (const float*)d_in[4];   // [2048,8]
    const float* A2 = (const float*)d_in[5];   // [8,2048]
    const float* B2 = (const float*)d_in[6];   // [2048,8]
    float* out = (float*)d_out;

    const int d = 2048;
    const int K = d;               // in_features
    const int N = 3 * d;           // 6144 fused rows
    const int M = in_sizes[0] / d; // 8192 = B*S

    unsigned short* Xbf = (unsigned short*)d_ws;              // M*K bf16 = 33.5 MB
    unsigned short* Wbf = Xbf + (size_t)M * K;                // N*K bf16 = 25.2 MB

    // 1) fused: Wb = bf16(W + delta); Xb = bf16(x)   [unchanged]
    int n8 = (M * K) / 8;
    int castBlocks = (n8 + 255) / 256;
    prep_kernel<<<N + castBlocks, 256, 0, stream>>>(x, W, A1, B1, A2, B2,
                                                    Xbf, Wbf, d, N, n8);

    // 2) GEMM + bias: 256x256 tiles, quadrant schedule, deep counted-vmcnt staging
    dim3 grid((M / BM) * (N / BN));   // 32*24 = 768
    gemm256_kernel<<<grid, 512, 0, stream>>>(Xbf, Wbf, b, out, M);
}